// Round 2
// baseline (12.735 us; speedup 1.0000x reference)
//
#include <hip/hip_runtime.h>
#include <math.h>

#define H 128

__device__ __forceinline__ float sigmoidf_(float x) {
    return 1.0f / (1.0f + __expf(-x));
}

// One wave (64 lanes) per output element j. 128 blocks x 64 threads.
// The wave computes all three gate rows (r=j, z=j+128, n=j+256):
//   - x (512 floats) loaded once into registers, reused for all 3 w_ih rows
//   - 6 partial dot products reduced via independent pipelined butterflies
//   - biases / h0[j] are wave-uniform -> scalar loads issued at kernel top
// No LDS, no __syncthreads, no post-reduction dependent load chain.
__global__ __launch_bounds__(64) void gru_fwd_cell_kernel(
    const float* __restrict__ x,      // (512,)
    const float* __restrict__ h0,     // (2,1,128) -> forward dir = h0[0..127]
    const float* __restrict__ w_ih,   // (384,512) row-major
    const float* __restrict__ w_hh,   // (384,128) row-major
    const float* __restrict__ b_ih,   // (384,)
    const float* __restrict__ b_hh,   // (384,)
    float* __restrict__ out)          // (128,)
{
    const int j    = blockIdx.x;      // output index 0..127
    const int lane = threadIdx.x;     // 0..63

    // Wave-uniform loads (become s_load, issued early, latency hidden).
    const float bih_r = b_ih[j];
    const float bih_z = b_ih[j + 128];
    const float bih_n = b_ih[j + 256];
    const float bhh_r = b_hh[j];
    const float bhh_z = b_hh[j + 128];
    const float bhh_n = b_hh[j + 256];
    const float hj    = h0[j];        // forward hidden state element

    // x into registers: 512 floats = 128 float4; lane takes idx lane, lane+64.
    const float4* x4 = reinterpret_cast<const float4*>(x);
    const float4 xv0 = x4[lane];
    const float4 xv1 = x4[lane + 64];

    // h into registers: 128 floats = 64 float2.
    const float2* h2 = reinterpret_cast<const float2*>(h0);
    const float2 hv  = h2[lane];

    float aX[3], aH[3];
    #pragma unroll
    for (int g = 0; g < 3; ++g) {
        const int row = j + (g << 7);
        const float4* w4 = reinterpret_cast<const float4*>(w_ih + (size_t)row * 512);
        const float4 wa = w4[lane];
        const float4 wb = w4[lane + 64];
        aX[g] = wa.x * xv0.x + wa.y * xv0.y + wa.z * xv0.z + wa.w * xv0.w
              + wb.x * xv1.x + wb.y * xv1.y + wb.z * xv1.z + wb.w * xv1.w;

        const float2* wh2 = reinterpret_cast<const float2*>(w_hh + (size_t)row * H);
        const float2 wh = wh2[lane];
        aH[g] = wh.x * hv.x + wh.y * hv.y;
    }

    // Six independent butterfly reductions — chains pipeline across each step.
    #pragma unroll
    for (int m = 32; m >= 1; m >>= 1) {
        #pragma unroll
        for (int g = 0; g < 3; ++g) {
            aX[g] += __shfl_xor(aX[g], m, 64);
            aH[g] += __shfl_xor(aH[g], m, 64);
        }
    }

    if (lane == 0) {
        const float r = sigmoidf_(aX[0] + bih_r + aH[0] + bhh_r);
        const float z = sigmoidf_(aX[1] + bih_z + aH[1] + bhh_z);
        const float n = tanhf(aX[2] + bih_n + r * (aH[2] + bhh_n));
        out[j] = (1.0f - z) * n + z * hj;
    }
}

extern "C" void kernel_launch(void* const* d_in, const int* in_sizes, int n_in,
                              void* d_out, int out_size, void* d_ws, size_t ws_size,
                              hipStream_t stream) {
    const float* x    = (const float*)d_in[0];   // (1,512)
    const float* h0   = (const float*)d_in[1];   // (2,1,128)
    const float* w_ih = (const float*)d_in[2];   // (384,512)
    const float* w_hh = (const float*)d_in[3];   // (384,128)
    const float* b_ih = (const float*)d_in[4];   // (384,)
    const float* b_hh = (const float*)d_in[5];   // (384,)
    float* out = (float*)d_out;                  // (1,128)

    gru_fwd_cell_kernel<<<H, 64, 0, stream>>>(x, h0, w_ih, w_hh, b_ih, b_hh, out);
}

// Round 3
// 9.442 us; speedup vs baseline: 1.3487x; 1.3487x over previous
//
#include <hip/hip_runtime.h>
#include <math.h>

#define H 128

__device__ __forceinline__ float wave_reduce_sum(float v) {
    // full 64-lane wavefront reduction (CDNA wave = 64, not 32)
    #pragma unroll
    for (int m = 32; m >= 1; m >>= 1) v += __shfl_xor(v, m, 64);
    return v;
}

__device__ __forceinline__ float sigmoidf_(float x) {
    return 1.0f / (1.0f + __expf(-x));
}

// One block per output element j (128 blocks), 3 waves per block;
// wave w handles gate row (j + 128*w): w=0 -> r, w=1 -> z, w=2 -> n.
// Wave-uniform bias / h0 loads hoisted to entry (latency hidden under the
// vector loads); biases folded into the wave partials pre-LDS so the
// post-barrier tail is only: 6 LDS reads -> activations -> store.
__global__ __launch_bounds__(192) void gru_fwd_cell_kernel(
    const float* __restrict__ x,      // (512,)
    const float* __restrict__ h0,     // (2,1,128) -> forward dir = h0[0..127]
    const float* __restrict__ w_ih,   // (384,512) row-major
    const float* __restrict__ w_hh,   // (384,128) row-major
    const float* __restrict__ b_ih,   // (384,)
    const float* __restrict__ b_hh,   // (384,)
    float* __restrict__ out)          // (128,)
{
    const int j    = blockIdx.x;        // output index 0..127
    const int tid  = threadIdx.x;       // 0..191
    const int wave = tid >> 6;          // 0..2
    const int lane = tid & 63;          // 0..63

    const int row = j + (wave << 7);    // gate row in [0,384)

    // Wave-uniform loads, issued at kernel top (scalar path, latency hidden).
    const float bih = b_ih[row];
    const float bhh = b_hh[row];
    const float hj  = h0[j];            // forward hidden state element

    // ---- w_ih[row] . x : 512 floats = 128 float4; lanes take f4 idx lane, lane+64
    const float4* wih4 = reinterpret_cast<const float4*>(w_ih + (size_t)row * 512);
    const float4* x4   = reinterpret_cast<const float4*>(x);
    float accX = 0.0f;
    #pragma unroll
    for (int s = 0; s < 2; ++s) {
        const int idx = lane + (s << 6);
        float4 wv = wih4[idx];
        float4 xv = x4[idx];
        accX += wv.x * xv.x + wv.y * xv.y + wv.z * xv.z + wv.w * xv.w;
    }

    // ---- w_hh[row] . h : 128 floats = 64 float2; lane takes f2 idx lane
    const float2* whh2 = reinterpret_cast<const float2*>(w_hh + (size_t)row * H);
    const float2* h2   = reinterpret_cast<const float2*>(h0);  // forward dir
    float accH;
    {
        float2 wv = whh2[lane];
        float2 hv = h2[lane];
        accH = wv.x * hv.x + wv.y * hv.y;
    }

    accX = wave_reduce_sum(accX);
    accH = wave_reduce_sum(accH);

    __shared__ float sX[3];
    __shared__ float sH[3];
    if (lane == 0) {
        sX[wave] = accX + bih;   // bias folded in pre-LDS
        sH[wave] = accH + bhh;
    }
    __syncthreads();

    if (tid == 0) {
        const float r = sigmoidf_(sX[0] + sH[0]);
        const float z = sigmoidf_(sX[1] + sH[1]);
        const float n = tanhf(sX[2] + r * sH[2]);
        out[j] = (1.0f - z) * n + z * hj;
    }
}

extern "C" void kernel_launch(void* const* d_in, const int* in_sizes, int n_in,
                              void* d_out, int out_size, void* d_ws, size_t ws_size,
                              hipStream_t stream) {
    const float* x    = (const float*)d_in[0];   // (1,512)
    const float* h0   = (const float*)d_in[1];   // (2,1,128)
    const float* w_ih = (const float*)d_in[2];   // (384,512)
    const float* w_hh = (const float*)d_in[3];   // (384,128)
    const float* b_ih = (const float*)d_in[4];   // (384,)
    const float* b_hh = (const float*)d_in[5];   // (384,)
    float* out = (float*)d_out;                  // (1,128)

    gru_fwd_cell_kernel<<<H, 192, 0, stream>>>(x, h0, w_ih, w_hh, b_ih, b_hh, out);
}